// Round 8
// baseline (180.436 us; speedup 1.0000x reference)
//
#include <hip/hip_runtime.h>
#include <hip/hip_cooperative_groups.h>

#define CC 8
#define KK 64
#define BB 8192
#define NCHUNK 16
#define NBLK (NCHUNK * CC)            // 128 gram blocks
#define ROWS_PER_CHUNK (BB / NCHUNK)  // 512

// ---------------- workspace layout (bytes); everything fully rewritten each call ---------
#define OFF_GPART 0                   // f32 Gpart[128][4096]  = 2097152
#define OFF_SPART 2097152             // f32 Spart[128][64]    =   32768
#define OFF_CPART 2129920             // int cpart[128]        =     512
#define OFF_FPART 2130432             // int fpart[128]        =     512
#define OFF_G     2130944             // f64 G[8][4096]        =  262144
#define OFF_GSUM  2393088             // f32 gsum[8][64]       =    2048
#define OFF_GCNT  2395136             // int gcount[8]         =      32
#define OFF_GFST  2395168             // int gfirst[8]         =      32
#define OFF_INV   2395200             // f64 invS2[4096]       =   32768
#define OFF_LOG   2427968             // f64 logdets[9]        =      72

#define SMEM_DOUBLES 13120            // 104960 B: bufA 4160 | bufB 4160 | panelb 512 | Lb 4160 | Ldi 64 | mb 64

__device__ __forceinline__ double readlane_f64(double v, int lane) {
  union { double d; int i[2]; } u, r;
  u.d = v;
  r.i[0] = __builtin_amdgcn_readlane(u.i[0], lane);
  r.i[1] = __builtin_amdgcn_readlane(u.i[1], lane);
  return r.d;
}

// ================= P0: gram + stats, all outputs non-atomic per-(chunk,class) ============
__device__ __forceinline__ void phase_gram(const float* __restrict__ mu,
                                           const int* __restrict__ labels,
                                           char* ws, double* smem, int blk) {
  int chunk = blk >> 3, c = blk & 7;
  int tid = threadIdx.x;
  int lane = tid & 63, w = tid >> 6;
  int tx = tid & 15, ty = tid >> 4;
  float* rows = (float*)smem;               // [64][64] = 16 KB
  int* labs = (int*)(smem + 2048);          // 64 ints
  float* ssum = (float*)(smem + 2080);      // 64 f32
  int* scnt = (int*)(smem + 2112);          // 4 ints
  int* sfst = (int*)(smem + 2114);          // 4 ints
  float* Gpart = (float*)(ws + OFF_GPART);
  float* Spart = (float*)(ws + OFF_SPART);
  int* cpart = (int*)(ws + OFF_CPART);
  int* fpart = (int*)(ws + OFF_FPART);

  double acc[4][4] = {{0.0}};
  float rsum = 0.f;
  int cnt = 0, first = BB;
  int base = chunk * ROWS_PER_CHUNK;
  const float4* mu4 = (const float4*)mu + (size_t)base * (KK / 4);
  if (tid < KK) ssum[tid] = 0.f;

  float4 pf[4];
  int plab = 0;
#pragma unroll
  for (int i = 0; i < 4; ++i) pf[i] = mu4[tid + i * 256];
  if (tid < 64) plab = labels[base + tid];

#pragma unroll 1
  for (int g = 0; g < ROWS_PER_CHUNK / 64; ++g) {
    __syncthreads();
    float4* rows4 = (float4*)rows;
#pragma unroll
    for (int i = 0; i < 4; ++i) rows4[tid + i * 256] = pf[i];
    if (tid < 64) labs[tid] = plab;
    __syncthreads();
    if (g + 1 < ROWS_PER_CHUNK / 64) {
#pragma unroll
      for (int i = 0; i < 4; ++i) pf[i] = mu4[(g + 1) * 1024 + tid + i * 256];
      if (tid < 64) plab = labels[base + (g + 1) * 64 + tid];
    }
#pragma unroll 4
    for (int r = 0; r < 16; ++r) {
      int rr = w * 16 + r;
      if (labs[rr] == c) rsum += rows[rr * KK + lane];
    }
    if (lane < 16 && labs[w * 16 + lane] == c) {
      cnt++;
      first = min(first, base + g * 64 + w * 16 + lane);
    }
    unsigned long long m = __ballot(labs[lane] == c);
    while (m) {
      int r = __builtin_ctzll(m);
      m &= m - 1;
      const float4* rw4 = (const float4*)(rows + r * KK);
      float4 a4 = rw4[ty], b4 = rw4[tx];
      const float* ai = (const float*)&a4;
      const float* bj = (const float*)&b4;
#pragma unroll
      for (int a = 0; a < 4; ++a)
#pragma unroll
        for (int b = 0; b < 4; ++b) acc[a][b] += (double)ai[a] * (double)bj[b];
    }
  }
  int slot = chunk * CC + c;
  float* Gp = Gpart + (size_t)slot * KK * KK;
#pragma unroll
  for (int a = 0; a < 4; ++a)
#pragma unroll
    for (int b = 0; b < 4; ++b)
      Gp[(ty * 4 + a) * KK + tx * 4 + b] = (float)acc[a][b];
  atomicAdd(&ssum[lane], rsum);             // LDS-only atomic
#pragma unroll
  for (int off = 32; off; off >>= 1) {      // lanes >=16 hold 0 / BB: harmless
    cnt += __shfl_down(cnt, off);
    first = min(first, __shfl_down(first, off));
  }
  if (lane == 0) { scnt[w] = cnt; sfst[w] = first; }
  __syncthreads();
  if (tid < KK) Spart[(size_t)slot * KK + tid] = ssum[tid];
  if (tid == 0) {
    cpart[slot] = scnt[0] + scnt[1] + scnt[2] + scnt[3];
    fpart[slot] = min(min(sfst[0], sfst[1]), min(sfst[2], sfst[3]));
  }
}

// ================= shared: 4-wave blocked Cholesky (panel=8, rolled) =====================
__device__ __forceinline__ void chol64(double* smem, bool isS2, int blk,
                                       double* __restrict__ logdets_g) {
  int tid = threadIdx.x;
  int t = tid & 63, w = tid >> 6;
  double (*bufA)[KK + 1] = (double (*)[KK + 1])smem;
  double (*bufB)[KK + 1] = (double (*)[KK + 1])(smem + 4160);
  double (*panelb)[KK] = (double (*)[KK])(smem + 8320);
  double (*Lb)[KK + 1] = (double (*)[KK + 1])(smem + 8832);
  double* Ldi = smem + 12992;
  double (*cur)[KK + 1] = bufA;
  double (*nxt)[KK + 1] = bufB;
  double ldacc = 0.0;
  int bound = t | 7;
#pragma unroll 1
  for (int p = 0; p < 8; ++p) {
    const int P0 = p * 8;
    double cc_[8];
#pragma unroll
    for (int m = 0; m < 8; ++m) cc_[m] = cur[t][P0 + m];
    double uu[8];
    double pd = 1.0;
#pragma unroll
    for (int m = 0; m < 8; ++m) {
      double akk = readlane_f64(cc_[m], P0 + m);
      pd *= akk;
      double inv;
      asm("v_rcp_f64 %0, %1" : "=v"(inv) : "v"(akk));
      inv = inv * fma(-akk, inv, 2.0);         // 1 Newton: rel err ~4e-9
      uu[m] = cc_[m] * inv;
      if (w == 0) {
        panelb[m][t] = cc_[m];
        if (isS2) {
          double rsv = sqrt(akk) * inv;        // 1/sqrt(akk)
          Lb[t][P0 + m] = cc_[m] * rsv;
          if (t == 0) Ldi[P0 + m] = rsv;
        }
      }
#pragma unroll
      for (int mm = m + 1; mm < 8; ++mm)
        cc_[mm] -= uu[m] * readlane_f64(cc_[m], P0 + mm);
    }
    ldacc += log(pd);
    __syncthreads();                           // panelb visible
#pragma unroll 1
    for (int jb = p + 1 + w; jb < 8; jb += 4) {
      int j = jb * 8;
      if (j <= bound) {
        double aj[8];
#pragma unroll
        for (int q = 0; q < 8; ++q) aj[q] = cur[t][j + q];
#pragma unroll
        for (int m = 0; m < 8; ++m)
#pragma unroll
          for (int q = 0; q < 8; ++q) aj[q] -= uu[m] * panelb[m][j + q];
#pragma unroll
        for (int q = 0; q < 8; ++q) nxt[t][j + q] = aj[q];
      }
    }
    __syncthreads();
    { auto tmp = cur; cur = nxt; nxt = tmp; }  // after 8 swaps cur == bufA
  }
  if (tid == 0) logdets_g[blk] = ldacc;
}

// ================= P1 (blocks 0-7): stats reduce + fused G-reduce/build + Cholesky =======
__device__ __forceinline__ void phase_class(const float* __restrict__ cov,
                                            char* ws, double* smem, int c) {
  int tid = threadIdx.x;
  float* Spart = (float*)(ws + OFF_SPART);
  int* cpart = (int*)(ws + OFF_CPART);
  int* fpart = (int*)(ws + OFF_FPART);
  float* Gpart = (float*)(ws + OFF_GPART);
  double* Gg = (double*)(ws + OFF_G);
  float* gsum = (float*)(ws + OFF_GSUM);
  int* gcount = (int*)(ws + OFF_GCNT);
  int* gfirst = (int*)(ws + OFF_GFST);
  double* mb = smem + 13056;     // 64 doubles
  double* tmp = smem + 12992;    // Ldi area unused for !isS2

  if (tid < KK) {
    double s = 0.0;
#pragma unroll
    for (int p = 0; p < NCHUNK; ++p) s += (double)Spart[(size_t)(p * CC + c) * KK + tid];
    gsum[c * KK + tid] = (float)s;
    mb[tid] = s;                 // raw sum; divide once count known
  } else if (tid == 64) {
    int ct = 0;
#pragma unroll
    for (int p = 0; p < NCHUNK; ++p) ct += cpart[p * CC + c];
    gcount[c] = ct;
    tmp[0] = (double)ct;
  } else if (tid == 65) {
    int ff = BB;
#pragma unroll
    for (int p = 0; p < NCHUNK; ++p) ff = min(ff, fpart[p * CC + c]);
    gfirst[c] = ff;
  }
  __syncthreads();
  double ncd = tmp[0];
  double safe = ncd > 0.0 ? ncd : 1.0;
  double inv_safe = 1.0 / safe;
  if (tid < KK) mb[tid] *= inv_safe;   // mean
  __syncthreads();

  double (*bufA)[KK + 1] = (double (*)[KK + 1])smem;
#pragma unroll 1
  for (int e = tid; e < KK * KK; e += 256) {
    double g = 0.0;
#pragma unroll
    for (int p = 0; p < NCHUNK; ++p) g += (double)Gpart[(size_t)(p * CC + c) * KK * KK + e];
    Gg[(size_t)c * KK * KK + e] = g;                 // f64 G[c] for combine + Sigma_total
    int tt = e & 63, jj = e >> 6;                     // cov, G symmetric: e works either way
    bufA[tt][jj] = (double)cov[e] + (g - ncd * mb[tt] * mb[jj]) * inv_safe;
  }
  __syncthreads();
  chol64(smem, false, c, (double*)(ws + OFF_LOG));
}

// ================= P2 (block 8): Sigma_total build + Cholesky + solve + XtX ==============
__device__ __forceinline__ void phase_total(const float* __restrict__ cov,
                                            char* ws, double* smem) {
  int tid = threadIdx.x;
  int t = tid & 63, w = tid >> 6;
  double* Gg = (double*)(ws + OFF_G);
  float* gsum = (float*)(ws + OFF_GSUM);
  double* mb = smem + 13056;

  if (tid < KK) {
    double s = 0.0;
#pragma unroll
    for (int c = 0; c < CC; ++c) s += (double)gsum[c * KK + tid];
    mb[tid] = s / (double)BB;
  }
  __syncthreads();
  double (*bufA)[KK + 1] = (double (*)[KK + 1])smem;
  const double invB = 1.0 / (double)BB;
#pragma unroll 1
  for (int e = tid; e < KK * KK; e += 256) {
    double g = 0.0;
#pragma unroll
    for (int c = 0; c < CC; ++c) g += Gg[(size_t)c * KK * KK + e];
    int tt = e & 63, jj = e >> 6;
    bufA[tt][jj] = (double)cov[e] + g * invB - mb[tt] * mb[jj];
  }
  __syncthreads();
  chol64(smem, true, CC, (double*)(ws + OFF_LOG));

  // X = L^{-1}: wave 0, column t per lane; Xs overlays bufA (only Lb/Ldi read)
  double (*Xs)[KK] = (double (*)[KK])smem;
  double (*Lb)[KK + 1] = (double (*)[KK + 1])(smem + 8832);
  double* Ldi = smem + 12992;
  if (w == 0) {
#pragma unroll 1
    for (int g = 0; g < 8; ++g) {
      int I0 = g * 8;
      double sv[8];
#pragma unroll
      for (int m = 0; m < 8; ++m) sv[m] = 0.0;
#pragma unroll 2
      for (int j = 0; j < I0; ++j) {
        double xj = Xs[j][t];
#pragma unroll
        for (int m = 0; m < 8; ++m) sv[m] += Lb[I0 + m][j] * xj;
      }
#pragma unroll
      for (int m = 0; m < 8; ++m) {
        int i = I0 + m;
        double x = (((i == t) ? 1.0 : 0.0) - sv[m]) * Ldi[i];
#pragma unroll
        for (int mm = m + 1; mm < 8; ++mm) sv[mm] += Lb[I0 + mm][i] * x;
        Xs[i][t] = x;
      }
    }
  }
  __syncthreads();
  double* invS2 = (double*)(ws + OFF_INV);
#pragma unroll 1
  for (int rr = 0; rr < 16; ++rr) {
    int r = w + rr * 4;
    int k0 = r > t ? r : t;
    double s = 0.0;
#pragma unroll 2
    for (int k = k0; k < KK; ++k) s += Xs[k][r] * Xs[k][t];
    invS2[r * KK + t] = s;
  }
}

// ================= P3 (blocks 0-7, wave 0): per-class KL + atomic combine ================
__device__ __forceinline__ void phase_combine(const float* __restrict__ cov,
                                              char* ws, float* out, double* smem, int c) {
  int t = threadIdx.x;
  if (t >= 64) return;
  double* Gg = (double*)(ws + OFF_G);
  double* invS2 = (double*)(ws + OFF_INV);
  double* logdets = (double*)(ws + OFF_LOG);
  float* gsum = (float*)(ws + OFF_GSUM);
  int* gcount = (int*)(ws + OFF_GCNT);
  int* gfirst = (int*)(ws + OFF_GFST);
  double* mv = smem;
  double* dv = smem + 64;

  double mtot = 0.0;
#pragma unroll
  for (int cc2 = 0; cc2 < CC; ++cc2) mtot += (double)gsum[cc2 * KK + t];
  mtot /= (double)BB;
  int nc = gcount[c];
  double safe = nc > 0 ? (double)nc : 1.0;
  double mt = (double)gsum[c * KK + t] / safe;
  double dt = mtot - mt;
  mv[t] = mt;
  dv[t] = dt;

  const double* Gc = Gg + (size_t)c * KK * KK;
  double tg = 0.0, qm = 0.0, qd = 0.0, tic = 0.0;
#pragma unroll 4
  for (int m = 0; m < KK; ++m) {
    double w2 = invS2[m * KK + t];
    tic += w2 * (double)cov[m * KK + t];
    tg += w2 * Gc[m * KK + t];
    qm += w2 * mv[m];
    qd += w2 * dv[m];
  }
  qm *= mt;
  qd *= dt;
#pragma unroll
  for (int m = 32; m; m >>= 1) {
    tg += __shfl_down(tg, m);
    qm += __shfl_down(qm, m);
    qd += __shfl_down(qd, m);
    tic += __shfl_down(tic, m);
  }
  if (t == 0) {
    int best = 0;
    long long bv = -2;
    for (int cc2 = 0; cc2 < CC; ++cc2) {
      long long v = gcount[cc2] > 0 ? (long long)gfirst[cc2] : -1;
      if (v > bv) { bv = v; best = cc2; }
    }
    double tr = tic + (tg - (double)nc * qm) / safe;
    double kl = 0.5 * (tr + qd - (double)KK + logdets[CC] - logdets[c]);
    double wgt = (nc > 0 && c != best) ? (double)nc : 0.0;
    atomicAdd(out, (float)(kl * wgt / (double)BB));
  }
}

// ================= cooperative mono-kernel ===============================================
__global__ void __launch_bounds__(256) fused_all(const float* __restrict__ mu,
                                                 const int* __restrict__ labels,
                                                 const float* __restrict__ cov,
                                                 float* out, char* ws) {
  __shared__ double smem[SMEM_DOUBLES];
  cooperative_groups::grid_group grid = cooperative_groups::this_grid();
  int blk = blockIdx.x;
  phase_gram(mu, labels, ws, smem, blk);
  grid.sync();
  if (blk < CC) phase_class(cov, ws, smem, blk);
  else if (blk == CC && threadIdx.x == 0) out[0] = 0.f;
  grid.sync();
  if (blk == CC) phase_total(cov, ws, smem);
  grid.sync();
  if (blk < CC) phase_combine(cov, ws, out, smem, blk);
}

// ================= fallback: same phases as classic dispatches ===========================
__global__ void __launch_bounds__(256) k_gram(const float* __restrict__ mu,
                                              const int* __restrict__ labels, char* ws) {
  __shared__ double smem[2176];
  phase_gram(mu, labels, ws, smem, blockIdx.x);
}
__global__ void __launch_bounds__(256) k_class(const float* __restrict__ cov,
                                               float* out, char* ws) {
  __shared__ double smem[SMEM_DOUBLES];
  if (blockIdx.x < CC) phase_class(cov, ws, smem, blockIdx.x);
  else if (threadIdx.x == 0) out[0] = 0.f;
}
__global__ void __launch_bounds__(256) k_total(const float* __restrict__ cov, char* ws) {
  __shared__ double smem[SMEM_DOUBLES];
  phase_total(cov, ws, smem);
}
__global__ void __launch_bounds__(256) k_combine(const float* __restrict__ cov,
                                                 float* out, char* ws) {
  __shared__ double smem[128];
  phase_combine(cov, ws, out, smem, blockIdx.x);
}

extern "C" void kernel_launch(void* const* d_in, const int* in_sizes, int n_in,
                              void* d_out, int out_size, void* d_ws, size_t ws_size,
                              hipStream_t stream) {
  (void)in_sizes; (void)n_in; (void)out_size; (void)ws_size;
  const float* mu = (const float*)d_in[0];
  const int* labels = (const int*)d_in[1];
  const float* cov = (const float*)d_in[2];
  float* out = (float*)d_out;
  char* ws = (char*)d_ws;

  void* args[] = {(void*)&mu, (void*)&labels, (void*)&cov, (void*)&out, (void*)&ws};
  hipError_t err = hipLaunchCooperativeKernel(
      reinterpret_cast<const void*>(fused_all), dim3(NBLK), dim3(256), args, 0, stream);
  if (err != hipSuccess) {
    // classic path: 4 dispatches, no memsets (all accumulators are non-atomic partials)
    k_gram<<<NBLK, 256, 0, stream>>>(mu, labels, ws);
    k_class<<<CC + 1, 256, 0, stream>>>(cov, out, ws);
    k_total<<<1, 256, 0, stream>>>(cov, ws);
    k_combine<<<CC, 256, 0, stream>>>(cov, out, ws);
  }
}

// Round 9
// 163.872 us; speedup vs baseline: 1.1011x; 1.1011x over previous
//
#include <hip/hip_runtime.h>

#define CC 8
#define KK 64
#define BB 8192
#define NCHUNK 16
#define NGBLK (NCHUNK * CC)            // 128 gram blocks
#define ROWS_PER_CHUNK (BB / NCHUNK)   // 512

// ---------------- workspace layout (bytes); fully rewritten each call --------------------
#define OFF_GPART 0                    // f32 Gpart[128][4096] = 2097152
#define OFF_SPART 2097152              // f32 Spart[128][64]   =   32768
#define OFF_CPART 2129920              // int cpart[128]       =     512
#define OFF_FPART 2130432              // int fpart[128]       =     512
#define OFF_GT    2130944              // f32 GT[16][4096]     =  262144  (per-chunk total gram)
#define OFF_TERMS 2393088              // f64 terms[8]         =      64
#define OFF_CNTR  2393152              // int counter          =      16

// ---------------- k_back LDS layout (double indices) -------------------------------------
#define SM_BUFA  0                     // [64][65]
#define SM_BUFB  4160                  // [64][65]
#define SM_PANEL 8320                  // [8][64]
#define SM_LB    8832                  // [64][65]
#define SM_LDI   12992                 // [64]
#define SM_MB    13056                 // [64] class mean
#define SM_MTOT  13120                 // [64] total mean
#define SM_DV    13184                 // [64] mtot - mb
#define SM_RED   13248                 // [8]
#define SM_INTS  13256                 // 4 doubles = 16 ints: cnt8[8], fst8[8]
#define SMEM_BACK 13260

__device__ __forceinline__ double readlane_f64(double v, int lane) {
  union { double d; int i[2]; } u, r;
  u.d = v;
  r.i[0] = __builtin_amdgcn_readlane(u.i[0], lane);
  r.i[1] = __builtin_amdgcn_readlane(u.i[1], lane);
  return r.d;
}

// ================= D1a: gram + stats, non-atomic per-(chunk,class) partials ==============
__device__ __forceinline__ void phase_gram(const float* __restrict__ mu,
                                           const int* __restrict__ labels,
                                           char* ws, double* smem, int blk) {
  int chunk = blk >> 3, c = blk & 7;
  int tid = threadIdx.x;
  int lane = tid & 63, w = tid >> 6;
  int tx = tid & 15, ty = tid >> 4;
  float* rows = (float*)smem;               // [64][64] = 16 KB
  int* labs = (int*)(smem + 2048);
  float* ssum = (float*)(smem + 2080);
  int* scnt = (int*)(smem + 2112);
  int* sfst = (int*)(smem + 2114);
  float* Gpart = (float*)(ws + OFF_GPART);
  float* Spart = (float*)(ws + OFF_SPART);
  int* cpart = (int*)(ws + OFF_CPART);
  int* fpart = (int*)(ws + OFF_FPART);

  double acc[4][4] = {{0.0}};
  float rsum = 0.f;
  int cnt = 0, first = BB;
  int base = chunk * ROWS_PER_CHUNK;
  const float4* mu4 = (const float4*)mu + (size_t)base * (KK / 4);
  if (tid < KK) ssum[tid] = 0.f;

  float4 pf[4];
  int plab = 0;
#pragma unroll
  for (int i = 0; i < 4; ++i) pf[i] = mu4[tid + i * 256];
  if (tid < 64) plab = labels[base + tid];

#pragma unroll 1
  for (int g = 0; g < ROWS_PER_CHUNK / 64; ++g) {
    __syncthreads();
    float4* rows4 = (float4*)rows;
#pragma unroll
    for (int i = 0; i < 4; ++i) rows4[tid + i * 256] = pf[i];
    if (tid < 64) labs[tid] = plab;
    __syncthreads();
    if (g + 1 < ROWS_PER_CHUNK / 64) {
#pragma unroll
      for (int i = 0; i < 4; ++i) pf[i] = mu4[(g + 1) * 1024 + tid + i * 256];
      if (tid < 64) plab = labels[base + (g + 1) * 64 + tid];
    }
#pragma unroll 4
    for (int r = 0; r < 16; ++r) {
      int rr = w * 16 + r;
      if (labs[rr] == c) rsum += rows[rr * KK + lane];
    }
    if (lane < 16 && labs[w * 16 + lane] == c) {
      cnt++;
      first = min(first, base + g * 64 + w * 16 + lane);
    }
    unsigned long long m = __ballot(labs[lane] == c);
    while (m) {
      int r = __builtin_ctzll(m);
      m &= m - 1;
      const float4* rw4 = (const float4*)(rows + r * KK);
      float4 a4 = rw4[ty], b4 = rw4[tx];
      const float* ai = (const float*)&a4;
      const float* bj = (const float*)&b4;
#pragma unroll
      for (int a = 0; a < 4; ++a)
#pragma unroll
        for (int b = 0; b < 4; ++b) acc[a][b] += (double)ai[a] * (double)bj[b];
    }
  }
  int slot = chunk * CC + c;
  float* Gp = Gpart + (size_t)slot * KK * KK;
#pragma unroll
  for (int a = 0; a < 4; ++a)
#pragma unroll
    for (int b = 0; b < 4; ++b)
      Gp[(ty * 4 + a) * KK + tx * 4 + b] = (float)acc[a][b];
  atomicAdd(&ssum[lane], rsum);             // LDS-only atomic
#pragma unroll
  for (int off = 32; off; off >>= 1) {
    cnt += __shfl_down(cnt, off);
    first = min(first, __shfl_down(first, off));
  }
  if (lane == 0) { scnt[w] = cnt; sfst[w] = first; }
  __syncthreads();
  if (tid < KK) Spart[(size_t)slot * KK + tid] = ssum[tid];
  if (tid == 0) {
    cpart[slot] = scnt[0] + scnt[1] + scnt[2] + scnt[3];
    fpart[slot] = min(min(sfst[0], sfst[1]), min(sfst[2], sfst[3]));
  }
}

// ================= D1b: per-chunk TOTAL gram partial (no label filter, f32 acc) ==========
__device__ __forceinline__ void phase_tgram(const float* __restrict__ mu,
                                            char* ws, double* smem, int chunk) {
  int tid = threadIdx.x;
  int tx = tid & 15, ty = tid >> 4;
  float* rows = (float*)smem;
  float* GT = (float*)(ws + OFF_GT);
  float acc[4][4] = {{0.f}};
  int base = chunk * ROWS_PER_CHUNK;
  const float4* mu4 = (const float4*)mu + (size_t)base * (KK / 4);
  float4 pf[4];
#pragma unroll
  for (int i = 0; i < 4; ++i) pf[i] = mu4[tid + i * 256];
#pragma unroll 1
  for (int g = 0; g < ROWS_PER_CHUNK / 64; ++g) {
    __syncthreads();
    float4* rows4 = (float4*)rows;
#pragma unroll
    for (int i = 0; i < 4; ++i) rows4[tid + i * 256] = pf[i];
    __syncthreads();
    if (g + 1 < ROWS_PER_CHUNK / 64) {
#pragma unroll
      for (int i = 0; i < 4; ++i) pf[i] = mu4[(g + 1) * 1024 + tid + i * 256];
    }
#pragma unroll 1
    for (int r = 0; r < 64; ++r) {
      const float4* rw4 = (const float4*)(rows + r * KK);
      float4 a4 = rw4[ty], b4 = rw4[tx];
      const float* ai = (const float*)&a4;
      const float* bj = (const float*)&b4;
#pragma unroll
      for (int a = 0; a < 4; ++a)
#pragma unroll
        for (int b = 0; b < 4; ++b) acc[a][b] += ai[a] * bj[b];
    }
  }
  float* Gp = GT + (size_t)chunk * KK * KK;
#pragma unroll
  for (int a = 0; a < 4; ++a)
#pragma unroll
    for (int b = 0; b < 4; ++b)
      Gp[(ty * 4 + a) * KK + tx * 4 + b] = acc[a][b];
}

__global__ __launch_bounds__(256) void k_front(const float* __restrict__ mu,
                                               const int* __restrict__ labels, char* ws) {
  __shared__ double smem[2176];
  int blk = blockIdx.x;
  if (blk < NGBLK) {
    phase_gram(mu, labels, ws, smem, blk);
  } else {
    if (blk == NGBLK && threadIdx.x == 0) *(int*)(ws + OFF_CNTR) = 0;  // reset epilogue counter
    phase_tgram(mu, ws, smem, blk - NGBLK);
  }
}

// ================= 4-wave blocked Cholesky (panel=8, rolled); returns logdet ============
__device__ __noinline__ double chol64(double* smem, bool isS2) {
  int tid = threadIdx.x;
  int t = tid & 63, w = tid >> 6;
  double (*bufA)[KK + 1] = (double (*)[KK + 1])(smem + SM_BUFA);
  double (*bufB)[KK + 1] = (double (*)[KK + 1])(smem + SM_BUFB);
  double (*panelb)[KK] = (double (*)[KK])(smem + SM_PANEL);
  double (*Lb)[KK + 1] = (double (*)[KK + 1])(smem + SM_LB);
  double* Ldi = smem + SM_LDI;
  double (*cur)[KK + 1] = bufA;
  double (*nxt)[KK + 1] = bufB;
  double ldacc = 0.0;
  int bound = t | 7;
#pragma unroll 1
  for (int p = 0; p < 8; ++p) {
    const int P0 = p * 8;
    double cc_[8];
#pragma unroll
    for (int m = 0; m < 8; ++m) cc_[m] = cur[t][P0 + m];
    double uu[8];
    double pd = 1.0;
#pragma unroll
    for (int m = 0; m < 8; ++m) {
      double akk = readlane_f64(cc_[m], P0 + m);   // uniform SGPR lane -> v_readlane
      pd *= akk;
      double inv;
      asm("v_rcp_f64 %0, %1" : "=v"(inv) : "v"(akk));
      inv = inv * fma(-akk, inv, 2.0);             // 1 Newton: rel err ~4e-9
      uu[m] = cc_[m] * inv;
      if (w == 0) {
        panelb[m][t] = cc_[m];
        if (isS2) {
          double rsv = sqrt(akk) * inv;            // 1/sqrt(akk)
          Lb[t][P0 + m] = cc_[m] * rsv;
          if (t == 0) Ldi[P0 + m] = rsv;
        }
      }
#pragma unroll
      for (int mm = m + 1; mm < 8; ++mm)
        cc_[mm] -= uu[m] * readlane_f64(cc_[m], P0 + mm);
    }
    ldacc += log(pd);
    __syncthreads();                    // panelb visible
#pragma unroll 1
    for (int jb = p + 1 + w; jb < 8; jb += 4) {
      int j = jb * 8;
      if (j <= bound) {
        double aj[8];
#pragma unroll
        for (int q = 0; q < 8; ++q) aj[q] = cur[t][j + q];
#pragma unroll
        for (int m = 0; m < 8; ++m)
#pragma unroll
          for (int q = 0; q < 8; ++q) aj[q] -= uu[m] * panelb[m][j + q];
#pragma unroll
        for (int q = 0; q < 8; ++q) nxt[t][j + q] = aj[q];
      }
    }
    __syncthreads();
    { auto tmp = cur; cur = nxt; nxt = tmp; }      // 8 swaps -> cur ends == bufA
  }
  return ldacc;                                    // uniform across threads
}

// ================= D2: per-class everything; last block writes out =======================
__global__ __launch_bounds__(256) void k_back(const float* __restrict__ cov,
                                              float* out, char* ws) {
  __shared__ double smem[SMEM_BACK];
  int c = blockIdx.x;
  int tid = threadIdx.x;
  int t = tid & 63, w = tid >> 6;
  float* Gpart = (float*)(ws + OFF_GPART);
  float* Spart = (float*)(ws + OFF_SPART);
  int* cpart = (int*)(ws + OFF_CPART);
  int* fpart = (int*)(ws + OFF_FPART);
  float* GT = (float*)(ws + OFF_GT);
  double* terms = (double*)(ws + OFF_TERMS);
  int* cntr = (int*)(ws + OFF_CNTR);
  int* cnt8 = (int*)(smem + SM_INTS);
  int* fst8 = cnt8 + 8;

  // ---- A: stats reduce (all classes' counts/firsts; own + total raw sums) ----
  if (tid < 64) {
    double so = 0.0, st = 0.0;
#pragma unroll 8
    for (int slot = 0; slot < 128; ++slot) {
      double v = (double)Spart[slot * KK + t];
      st += v;
      if ((slot & 7) == c) so += v;
    }
    smem[SM_MB + t] = so;        // raw; scale below
    smem[SM_MTOT + t] = st;
  } else if (tid < 72) {
    int j = tid - 64;
    int ct = 0, ff = BB;
#pragma unroll
    for (int p = 0; p < NCHUNK; ++p) {
      ct += cpart[p * CC + j];
      ff = min(ff, fpart[p * CC + j]);
    }
    cnt8[j] = ct;
    fst8[j] = ff;
  }
  __syncthreads();
  int nc = cnt8[c];
  double ncd = (double)nc;
  double safe = nc > 0 ? ncd : 1.0;
  double inv_safe = 1.0 / safe;
  if (tid < 64) {
    double m = smem[SM_MB + t] * inv_safe;
    double mt2 = smem[SM_MTOT + t] * (1.0 / (double)BB);
    smem[SM_MB + t] = m;
    smem[SM_MTOT + t] = mt2;
    smem[SM_DV + t] = mt2 - m;
  }
  __syncthreads();
  double* mb = smem + SM_MB;
  double* mtv = smem + SM_MTOT;
  double* dv = smem + SM_DV;

  // ---- B: build Sigma_c, chol -> ld1 ----
#pragma unroll 1
  for (int e = tid; e < KK * KK; e += 256) {
    double g = 0.0;
#pragma unroll
    for (int p = 0; p < NCHUNK; ++p) g += (double)Gpart[(size_t)(p * CC + c) * KK * KK + e];
    int r = e >> 6, col = e & 63;
    smem[SM_BUFA + r * (KK + 1) + col] =
        (double)cov[e] + (g - ncd * mb[r] * mb[col]) * inv_safe;
  }
  __syncthreads();
  double ld1 = chol64(smem, false);

  // ---- C: build Sigma_total (from GT partials), chol -> ld2 + Lb/Ldi ----
#pragma unroll 1
  for (int e = tid; e < KK * KK; e += 256) {
    double g = 0.0;
#pragma unroll
    for (int p = 0; p < NCHUNK; ++p) g += (double)GT[(size_t)p * KK * KK + e];
    int r = e >> 6, col = e & 63;
    smem[SM_BUFA + r * (KK + 1) + col] =
        (double)cov[e] + g * (1.0 / (double)BB) - mtv[r] * mtv[col];
  }
  __syncthreads();
  double ld2 = chol64(smem, true);

  // ---- D: X = L^{-1} (wave 0; Xs stride-64 overlays dead bufA) ----
  double (*Xs)[KK] = (double (*)[KK])(smem + SM_BUFA);
  if (w == 0) {
    double (*Lb)[KK + 1] = (double (*)[KK + 1])(smem + SM_LB);
    double* Ldi = smem + SM_LDI;
#pragma unroll 1
    for (int g = 0; g < 8; ++g) {
      int I0 = g * 8;
      double sv[8];
#pragma unroll
      for (int m = 0; m < 8; ++m) sv[m] = 0.0;
#pragma unroll 2
      for (int j = 0; j < I0; ++j) {
        double xj = Xs[j][t];                      // lane-consecutive
#pragma unroll
        for (int m = 0; m < 8; ++m) sv[m] += Lb[I0 + m][j] * xj;  // broadcast
      }
#pragma unroll
      for (int m = 0; m < 8; ++m) {
        int i = I0 + m;
        double x = (((i == t) ? 1.0 : 0.0) - sv[m]) * Ldi[i];
#pragma unroll
        for (int mm = m + 1; mm < 8; ++mm) sv[mm] += Lb[I0 + mm][i] * x;
        Xs[i][t] = x;                              // zeros for i<t fall out naturally
      }
    }
  }
  __syncthreads();

  // ---- E: fused xtx+combine: inv element produced -> consumed immediately ----
  // thread (w,t) covers rows r = w+4*rr, column t:
  //   tr  += inv[r][t] * Sigma_c[r][t]   (Sigma_c recomputed from cached Gpart)
  //   quad += dv[t] * inv[r][t] * dv[r]
  double trp = 0.0, qp = 0.0;
#pragma unroll 1
  for (int rr = 0; rr < 16; ++rr) {
    int r = w + rr * 4;
    int k0 = r > t ? r : t;
    double s = 0.0;
#pragma unroll 2
    for (int k = k0; k < KK; ++k) s += Xs[k][r] * Xs[k][t];   // broadcast x consecutive
    double g = 0.0;
#pragma unroll
    for (int p = 0; p < NCHUNK; ++p)
      g += (double)Gpart[(size_t)(p * CC + c) * KK * KK + r * KK + t];  // L2-hot
    double sig = (double)cov[r * KK + t] + (g - ncd * mb[r] * mb[t]) * inv_safe;
    trp += s * sig;
    qp += s * dv[r];
  }
  qp *= dv[t];
#pragma unroll
  for (int m2 = 32; m2; m2 >>= 1) {
    trp += __shfl_down(trp, m2);
    qp += __shfl_down(qp, m2);
  }
  if (t == 0) {
    smem[SM_RED + w * 2] = trp;
    smem[SM_RED + w * 2 + 1] = qp;
  }
  __syncthreads();

  // ---- F: per-class term; 8th arriver sums and writes out ----
  if (tid == 0) {
    double tr = smem[SM_RED] + smem[SM_RED + 2] + smem[SM_RED + 4] + smem[SM_RED + 6];
    double quad = smem[SM_RED + 1] + smem[SM_RED + 3] + smem[SM_RED + 5] + smem[SM_RED + 7];
    int best = 0;
    long long bv = -2;
    for (int j = 0; j < CC; ++j) {
      long long v = cnt8[j] > 0 ? (long long)fst8[j] : -1;
      if (v > bv) { bv = v; best = j; }            // strict > == argmax tie-break
    }
    double kl = 0.5 * (tr + quad - (double)KK + ld2 - ld1);
    double wgt = (nc > 0 && c != best) ? ncd : 0.0;
    double term = kl * wgt / (double)BB;
    atomicExch((unsigned long long*)&terms[c], (unsigned long long)__double_as_longlong(term));
    __threadfence();                               // order term before counter
    int old = atomicAdd(cntr, 1);
    if (old == CC - 1) {                           // last block: gather + write
      double s = 0.0;
      for (int j = 0; j < CC; ++j) s += atomicAdd(&terms[j], 0.0);  // coherent reads
      out[0] = (float)s;
    }
  }
}

extern "C" void kernel_launch(void* const* d_in, const int* in_sizes, int n_in,
                              void* d_out, int out_size, void* d_ws, size_t ws_size,
                              hipStream_t stream) {
  (void)in_sizes; (void)n_in; (void)out_size; (void)ws_size;
  const float* mu = (const float*)d_in[0];
  const int* labels = (const int*)d_in[1];
  const float* cov = (const float*)d_in[2];
  float* out = (float*)d_out;
  char* ws = (char*)d_ws;

  k_front<<<NGBLK + NCHUNK, 256, 0, stream>>>(mu, labels, ws);
  k_back<<<CC, 256, 0, stream>>>(cov, out, ws);
}

// Round 10
// 146.290 us; speedup vs baseline: 1.2334x; 1.1202x over previous
//
#include <hip/hip_runtime.h>

#define CC 8
#define KK 64
#define BB 8192
#define NCHUNK 16
#define NGBLK (NCHUNK * CC)            // 128 gram blocks
#define ROWS_PER_CHUNK (BB / NCHUNK)   // 512

// ---------------- workspace layout (bytes); fully rewritten each call --------------------
#define OFF_GPART 0                    // f32 Gpart[128][4096] = 2097152
#define OFF_SPART 2097152              // f32 Spart[128][64]   =   32768
#define OFF_CPART 2129920              // int cpart[128]       =     512
#define OFF_FPART 2130432              // int fpart[128]       =     512
#define OFF_SIGC  2130944              // f64 SigC[8][4096]    =  262144
#define OFF_INV   2393088              // f64 invS2[4096]      =   32768
#define OFF_MB    2425856              // f64 MB[8][64]        =    4096
#define OFF_MT    2429952              // f64 MT[64]           =     512
#define OFF_LOG   2430464              // f64 logdets[9]       =      72
#define OFF_CNT8  2430536              // int cnt8[8]          =      32
#define OFF_FST8  2430568              // int fst8[8]          =      32
#define OFF_TERMS 2430600              // f64 terms[8]         =      64
#define OFF_CNTR  2430664              // int counter          =       4

// ---------------- k_mid LDS layout (double indices) --------------------------------------
#define SM_BUFA  0                     // [64][65]
#define SM_BUFB  4160                  // [64][65]  (also stats scratch red[4][64])
#define SM_PANEL 8320                  // [8][64]
#define SM_LB    8832                  // [64][65]
#define SM_LDI   12992                 // [64]
#define SM_MB    13056                 // [64]
#define SM_INTS  13120                 // 16 ints: cnt8s[8], fst8s[8]
#define SMEM_MID 13128

__device__ __forceinline__ double readlane_f64(double v, int lane) {
  union { double d; int i[2]; } u, r;
  u.d = v;
  r.i[0] = __builtin_amdgcn_readlane(u.i[0], lane);
  r.i[1] = __builtin_amdgcn_readlane(u.i[1], lane);
  return r.d;
}

// ================= D1: gram + stats, non-atomic per-(chunk,class) partials ==============
__global__ __launch_bounds__(256) void k_front(const float* __restrict__ mu,
                                               const int* __restrict__ labels, char* ws) {
  __shared__ double smem[2176];
  int blk = blockIdx.x;
  int chunk = blk >> 3, c = blk & 7;
  int tid = threadIdx.x;
  int lane = tid & 63, w = tid >> 6;
  int tx = tid & 15, ty = tid >> 4;
  float* rows = (float*)smem;               // [64][64] = 16 KB
  int* labs = (int*)(smem + 2048);
  float* ssum = (float*)(smem + 2080);
  int* scnt = (int*)(smem + 2112);
  int* sfst = (int*)(smem + 2114);
  float* Gpart = (float*)(ws + OFF_GPART);
  float* Spart = (float*)(ws + OFF_SPART);
  int* cpart = (int*)(ws + OFF_CPART);
  int* fpart = (int*)(ws + OFF_FPART);
  if (blk == 0 && tid == 0) *(int*)(ws + OFF_CNTR) = 0;   // reset combine epilogue counter

  double acc[4][4] = {{0.0}};
  float rsum = 0.f;
  int cnt = 0, first = BB;
  int base = chunk * ROWS_PER_CHUNK;
  const float4* mu4 = (const float4*)mu + (size_t)base * (KK / 4);
  if (tid < KK) ssum[tid] = 0.f;

  float4 pf[4];
  int plab = 0;
#pragma unroll
  for (int i = 0; i < 4; ++i) pf[i] = mu4[tid + i * 256];
  if (tid < 64) plab = labels[base + tid];

#pragma unroll 1
  for (int g = 0; g < ROWS_PER_CHUNK / 64; ++g) {
    __syncthreads();
    float4* rows4 = (float4*)rows;
#pragma unroll
    for (int i = 0; i < 4; ++i) rows4[tid + i * 256] = pf[i];
    if (tid < 64) labs[tid] = plab;
    __syncthreads();
    if (g + 1 < ROWS_PER_CHUNK / 64) {
#pragma unroll
      for (int i = 0; i < 4; ++i) pf[i] = mu4[(g + 1) * 1024 + tid + i * 256];
      if (tid < 64) plab = labels[base + (g + 1) * 64 + tid];
    }
#pragma unroll 4
    for (int r = 0; r < 16; ++r) {
      int rr = w * 16 + r;
      if (labs[rr] == c) rsum += rows[rr * KK + lane];
    }
    if (lane < 16 && labs[w * 16 + lane] == c) {
      cnt++;
      first = min(first, base + g * 64 + w * 16 + lane);
    }
    unsigned long long m = __ballot(labs[lane] == c);
    while (m) {
      int r = __builtin_ctzll(m);
      m &= m - 1;
      const float4* rw4 = (const float4*)(rows + r * KK);
      float4 a4 = rw4[ty], b4 = rw4[tx];
      const float* ai = (const float*)&a4;
      const float* bj = (const float*)&b4;
#pragma unroll
      for (int a = 0; a < 4; ++a)
#pragma unroll
        for (int b = 0; b < 4; ++b) acc[a][b] += (double)ai[a] * (double)bj[b];
    }
  }
  int slot = chunk * CC + c;
  float* Gp = Gpart + (size_t)slot * KK * KK;
#pragma unroll
  for (int a = 0; a < 4; ++a) {
    float4 v = make_float4((float)acc[a][0], (float)acc[a][1], (float)acc[a][2], (float)acc[a][3]);
    *(float4*)(Gp + (ty * 4 + a) * KK + tx * 4) = v;
  }
  atomicAdd(&ssum[lane], rsum);             // LDS-only atomic
#pragma unroll
  for (int off = 32; off; off >>= 1) {
    cnt += __shfl_down(cnt, off);
    first = min(first, __shfl_down(first, off));
  }
  if (lane == 0) { scnt[w] = cnt; sfst[w] = first; }
  __syncthreads();
  if (tid < KK) Spart[(size_t)slot * KK + tid] = ssum[tid];
  if (tid == 0) {
    cpart[slot] = scnt[0] + scnt[1] + scnt[2] + scnt[3];
    fpart[slot] = min(min(sfst[0], sfst[1]), min(sfst[2], sfst[3]));
  }
}

// ================= 4-wave blocked Cholesky (panel=8, rolled); returns logdet ============
__device__ __noinline__ double chol64(double* smem, bool isS2) {
  int tid = threadIdx.x;
  int t = tid & 63, w = tid >> 6;
  double (*bufA)[KK + 1] = (double (*)[KK + 1])(smem + SM_BUFA);
  double (*bufB)[KK + 1] = (double (*)[KK + 1])(smem + SM_BUFB);
  double (*panelb)[KK] = (double (*)[KK])(smem + SM_PANEL);
  double (*Lb)[KK + 1] = (double (*)[KK + 1])(smem + SM_LB);
  double* Ldi = smem + SM_LDI;
  double (*cur)[KK + 1] = bufA;
  double (*nxt)[KK + 1] = bufB;
  double ldacc = 0.0;
  int bound = t | 7;
#pragma unroll 1
  for (int p = 0; p < 8; ++p) {
    const int P0 = p * 8;
    double cc_[8];
#pragma unroll
    for (int m = 0; m < 8; ++m) cc_[m] = cur[t][P0 + m];
    double uu[8];
    double pd = 1.0;
#pragma unroll
    for (int m = 0; m < 8; ++m) {
      double akk = readlane_f64(cc_[m], P0 + m);   // uniform SGPR lane -> v_readlane
      pd *= akk;
      double inv;
      asm("v_rcp_f64 %0, %1" : "=v"(inv) : "v"(akk));
      inv = inv * fma(-akk, inv, 2.0);             // 1 Newton: rel err ~4e-9
      uu[m] = cc_[m] * inv;
      if (w == 0) {
        panelb[m][t] = cc_[m];
        if (isS2) {
          double rsv = sqrt(akk) * inv;            // 1/sqrt(akk)
          Lb[t][P0 + m] = cc_[m] * rsv;
          if (t == 0) Ldi[P0 + m] = rsv;
        }
      }
#pragma unroll
      for (int mm = m + 1; mm < 8; ++mm)
        cc_[mm] -= uu[m] * readlane_f64(cc_[m], P0 + mm);
    }
    ldacc += log(pd);
    __syncthreads();                    // panelb visible
#pragma unroll 1
    for (int jb = p + 1 + w; jb < 8; jb += 4) {
      int j = jb * 8;
      if (j <= bound) {
        double aj[8];
#pragma unroll
        for (int q = 0; q < 8; ++q) aj[q] = cur[t][j + q];
#pragma unroll
        for (int m = 0; m < 8; ++m)
#pragma unroll
          for (int q = 0; q < 8; ++q) aj[q] -= uu[m] * panelb[m][j + q];
#pragma unroll
        for (int q = 0; q < 8; ++q) nxt[t][j + q] = aj[q];
      }
    }
    __syncthreads();
    { auto tmp = cur; cur = nxt; nxt = tmp; }      // 8 swaps -> cur ends == bufA
  }
  return ldacc;                                    // uniform across threads
}

// ================= D2: 9 blocks: class Sigma+chol / total Sigma+chol+solve+xtx ==========
__global__ __launch_bounds__(256) void k_mid(const float* __restrict__ cov, char* ws) {
  __shared__ double smem[SMEM_MID];
  int blk = blockIdx.x;
  int tid = threadIdx.x;
  int t = tid & 63, w = tid >> 6;
  float* Gpart = (float*)(ws + OFF_GPART);
  float* Spart = (float*)(ws + OFF_SPART);
  int* cpart = (int*)(ws + OFF_CPART);
  int* fpart = (int*)(ws + OFF_FPART);
  double* SigC = (double*)(ws + OFF_SIGC);
  double* invS2 = (double*)(ws + OFF_INV);
  double* MBg = (double*)(ws + OFF_MB);
  double* MTg = (double*)(ws + OFF_MT);
  double* logdets = (double*)(ws + OFF_LOG);
  double* red = smem + SM_BUFB;                 // [4][64] scratch (pre-chol)
  double* mb = smem + SM_MB;
  int* cnt8s = (int*)(smem + SM_INTS);
  int* fst8s = cnt8s + 8;
  const float4* cov4 = (const float4*)cov;

  if (blk < CC) {
    int c = blk;
    // ---- A: stats, parallelized ----
    if (tid < 16) { if (tid < 8) cnt8s[tid] = 0; else fst8s[tid - 8] = BB; }
    __syncthreads();
    {
      double s = 0.0;
#pragma unroll
      for (int p = 0; p < 4; ++p) s += (double)Spart[((4 * w + p) * CC + c) * KK + t];
      red[w * KK + t] = s;
    }
    if (tid >= 64 && tid < 192) {
      int slot = tid - 64;
      atomicAdd(&cnt8s[slot & 7], cpart[slot]);
      atomicMin(&fst8s[slot & 7], fpart[slot]);
    }
    __syncthreads();
    int nc = cnt8s[c];
    double ncd = (double)nc;
    double safe = nc > 0 ? ncd : 1.0;
    double inv_safe = 1.0 / safe;
    if (tid < 64) {
      double s = (red[t] + red[KK + t] + red[2 * KK + t] + red[3 * KK + t]) * inv_safe;
      mb[t] = s;
      MBg[c * KK + t] = s;
    }
    if (blk == 0 && tid >= 192 && tid < 208) {     // publish cnt8/fst8 once
      int j = tid - 192;
      // written after the atomics completed (post-sync)
      if (j < 8) ((int*)(ws + OFF_CNT8))[j] = cnt8s[j];
      else ((int*)(ws + OFF_FST8))[j - 8] = fst8s[j - 8];
    }
    __syncthreads();
    // ---- B: vec4 Gpart reduce + build + SigC dump ----
#pragma unroll 1
    for (int q = 0; q < 4; ++q) {
      int base_e = tid * 16 + q * 4;
      double s0 = 0.0, s1 = 0.0, s2 = 0.0, s3 = 0.0;
#pragma unroll
      for (int p = 0; p < NCHUNK; ++p) {
        float4 v = ((const float4*)(Gpart + (size_t)(p * CC + c) * KK * KK))[base_e >> 2];
        s0 += (double)v.x; s1 += (double)v.y; s2 += (double)v.z; s3 += (double)v.w;
      }
      int r = base_e >> 6, c0 = base_e & 63;
      float4 cv = cov4[base_e >> 2];
      double mr = mb[r] * ncd;
      double v0 = (double)cv.x + (s0 - mr * mb[c0]) * inv_safe;
      double v1 = (double)cv.y + (s1 - mr * mb[c0 + 1]) * inv_safe;
      double v2 = (double)cv.z + (s2 - mr * mb[c0 + 2]) * inv_safe;
      double v3 = (double)cv.w + (s3 - mr * mb[c0 + 3]) * inv_safe;
      double* ba = smem + SM_BUFA + r * (KK + 1) + c0;
      ba[0] = v0; ba[1] = v1; ba[2] = v2; ba[3] = v3;
      double* sc = SigC + (size_t)c * KK * KK + base_e;
      sc[0] = v0; sc[1] = v1; sc[2] = v2; sc[3] = v3;
    }
    __syncthreads();
    double ld = chol64(smem, false);
    if (tid == 0) logdets[c] = ld;
  } else {
    // ---- block 8: total mean ----
    {
      double s = 0.0;
#pragma unroll 8
      for (int p = 0; p < 32; ++p) s += (double)Spart[(w * 32 + p) * KK + t];
      red[w * KK + t] = s;
    }
    __syncthreads();
    if (tid < 64) {
      double s = (red[t] + red[KK + t] + red[2 * KK + t] + red[3 * KK + t]) / (double)BB;
      mb[t] = s;
      MTg[t] = s;
    }
    __syncthreads();
    // ---- total gram reduce (all 128 slots) + build ----
    const double invB = 1.0 / (double)BB;
#pragma unroll 1
    for (int q = 0; q < 4; ++q) {
      int base_e = tid * 16 + q * 4;
      double s0 = 0.0, s1 = 0.0, s2 = 0.0, s3 = 0.0;
#pragma unroll 16
      for (int p = 0; p < 128; ++p) {
        float4 v = ((const float4*)(Gpart + (size_t)p * KK * KK))[base_e >> 2];
        s0 += (double)v.x; s1 += (double)v.y; s2 += (double)v.z; s3 += (double)v.w;
      }
      int r = base_e >> 6, c0 = base_e & 63;
      float4 cv = cov4[base_e >> 2];
      double mr = mb[r];
      double* ba = smem + SM_BUFA + r * (KK + 1) + c0;
      ba[0] = (double)cv.x + s0 * invB - mr * mb[c0];
      ba[1] = (double)cv.y + s1 * invB - mr * mb[c0 + 1];
      ba[2] = (double)cv.z + s2 * invB - mr * mb[c0 + 2];
      ba[3] = (double)cv.w + s3 * invB - mr * mb[c0 + 3];
    }
    __syncthreads();
    double ld2 = chol64(smem, true);
    if (tid == 0) logdets[CC] = ld2;
    // ---- X = L^{-1} (wave 0; Xs stride-64 overlays dead bufA) ----
    double (*Xs)[KK] = (double (*)[KK])(smem + SM_BUFA);
    if (w == 0) {
      double (*Lb)[KK + 1] = (double (*)[KK + 1])(smem + SM_LB);
      double* Ldi = smem + SM_LDI;
#pragma unroll 1
      for (int g = 0; g < 8; ++g) {
        int I0 = g * 8;
        double sv[8];
#pragma unroll
        for (int m = 0; m < 8; ++m) sv[m] = 0.0;
#pragma unroll 2
        for (int j = 0; j < I0; ++j) {
          double xj = Xs[j][t];                    // lane-consecutive
#pragma unroll
          for (int m = 0; m < 8; ++m) sv[m] += Lb[I0 + m][j] * xj;  // broadcast
        }
#pragma unroll
        for (int m = 0; m < 8; ++m) {
          int i = I0 + m;
          double x = (((i == t) ? 1.0 : 0.0) - sv[m]) * Ldi[i];
#pragma unroll
          for (int mm = m + 1; mm < 8; ++mm) sv[mm] += Lb[I0 + mm][i] * x;
          Xs[i][t] = x;                            // zeros for i<t fall out naturally
        }
      }
    }
    __syncthreads();
    // ---- invS2 = X^T X ----
#pragma unroll 1
    for (int rr = 0; rr < 16; ++rr) {
      int r = w + rr * 4;
      int k0 = r > t ? r : t;
      double s = 0.0;
#pragma unroll 2
      for (int k = k0; k < KK; ++k) s += Xs[k][r] * Xs[k][t];   // broadcast x consecutive
      invS2[r * KK + t] = s;
    }
  }
}

// ================= D3: combine from stored f64 SigC/invS2; counter-gather out ============
__global__ __launch_bounds__(256) void k_combine(float* out, char* ws) {
  __shared__ double sdv[KK];
  __shared__ double wred[8];
  int c = blockIdx.x;
  int tid = threadIdx.x;
  int t = tid & 63, w = tid >> 6;
  double* SigC = (double*)(ws + OFF_SIGC);
  double* invS2 = (double*)(ws + OFF_INV);
  double* MBg = (double*)(ws + OFF_MB);
  double* MTg = (double*)(ws + OFF_MT);
  double* logdets = (double*)(ws + OFF_LOG);
  int* cnt8 = (int*)(ws + OFF_CNT8);
  int* fst8 = (int*)(ws + OFF_FST8);
  double* terms = (double*)(ws + OFF_TERMS);
  int* cntr = (int*)(ws + OFF_CNTR);

  if (tid < 64) sdv[t] = MTg[t] - MBg[c * KK + t];
  __syncthreads();
  const double* Sc = SigC + (size_t)c * KK * KK;
  double trp = 0.0, qp = 0.0;
#pragma unroll 4
  for (int rr = 0; rr < 16; ++rr) {
    int r = w * 16 + rr;
    double iv = invS2[r * KK + t];
    trp += iv * Sc[r * KK + t];
    qp += iv * sdv[r];
  }
  qp *= sdv[t];
#pragma unroll
  for (int m = 32; m; m >>= 1) {
    trp += __shfl_down(trp, m);
    qp += __shfl_down(qp, m);
  }
  if (t == 0) { wred[w * 2] = trp; wred[w * 2 + 1] = qp; }
  __syncthreads();
  if (tid == 0) {
    double tr = wred[0] + wred[2] + wred[4] + wred[6];
    double quad = wred[1] + wred[3] + wred[5] + wred[7];
    int nc = cnt8[c];
    int best = 0;
    long long bv = -2;
    for (int j = 0; j < CC; ++j) {
      long long v = cnt8[j] > 0 ? (long long)fst8[j] : -1;
      if (v > bv) { bv = v; best = j; }            // strict > == argmax tie-break
    }
    double kl = 0.5 * (tr + quad - (double)KK + logdets[CC] - logdets[c]);
    double wgt = (nc > 0 && c != best) ? (double)nc : 0.0;
    double term = kl * wgt / (double)BB;
    atomicExch((unsigned long long*)&terms[c], (unsigned long long)__double_as_longlong(term));
    __threadfence();                               // order term before counter
    int old = atomicAdd(cntr, 1);
    if (old == CC - 1) {                           // last arriver gathers + writes
      double s = 0.0;
      for (int j = 0; j < CC; ++j) s += atomicAdd(&terms[j], 0.0);  // coherent reads
      out[0] = (float)s;
    }
  }
}

extern "C" void kernel_launch(void* const* d_in, const int* in_sizes, int n_in,
                              void* d_out, int out_size, void* d_ws, size_t ws_size,
                              hipStream_t stream) {
  (void)in_sizes; (void)n_in; (void)out_size; (void)ws_size;
  const float* mu = (const float*)d_in[0];
  const int* labels = (const int*)d_in[1];
  const float* cov = (const float*)d_in[2];
  float* out = (float*)d_out;
  char* ws = (char*)d_ws;

  k_front<<<NGBLK, 256, 0, stream>>>(mu, labels, ws);
  k_mid<<<CC + 1, 256, 0, stream>>>(cov, ws);
  k_combine<<<CC, 256, 0, stream>>>(out, ws);
}

// Round 11
// 125.804 us; speedup vs baseline: 1.4343x; 1.1628x over previous
//
#include <hip/hip_runtime.h>

#define CC 8
#define KK 64
#define BB 8192
#define NCHUNK 16
#define NGBLK (NCHUNK * CC)            // 128 gram blocks
#define ROWS_PER_CHUNK (BB / NCHUNK)   // 512

// ---------------- workspace layout (bytes); fully rewritten each call --------------------
#define OFF_GPART 0                    // f32 Gpart[128][4096] = 2097152
#define OFF_SPART 2097152              // f32 Spart[128][64]   =   32768
#define OFF_CPART 2129920              // int cpart[128]       =     512
#define OFF_FPART 2130432              // int fpart[128]       =     512
#define OFF_GT    2130944              // f64 GT[4096]         =   32768 (zeroed by k_front)
#define OFF_INV   2163712              // f64 invS2[4096]      =   32768
#define OFF_LD2   2196480              // f64 logdet_total     =       8
#define OFF_TERMS 2196488              // f64 terms[8]         =      64
#define OFF_CNTR  2196552              // int term counter     =       4
#define OFF_RDY   2196556              // int G_c ready count  =       4
#define OFF_FLG   2196560              // int invS2 ready flag =       4

// ---------------- k_back LDS layout (double indices) -------------------------------------
#define SM_BUFA  0                     // [64][65] Sigma -> chol ping
#define SM_BUFB  4160                  // [64][65] chol pong (also stats scratch red[4][64])
#define SM_PANEL 8320                  // [8][64]  chol panel (also wred[8] post-chol)
#define SM_LB    8832                  // [64][65] class: Sigma_c stash | blk8: normalized L
#define SM_LDI   12992                 // [64]     class: dv            | blk8: 1/L[i][i]
#define SM_MB    13056                 // [64]     mean
#define SM_INTS  13120                 // 16 ints: cnt8s[8], fst8s[8]
#define SMEM_BACK 13128

__device__ __forceinline__ double readlane_f64(double v, int lane) {
  union { double d; int i[2]; } u, r;
  u.d = v;
  r.i[0] = __builtin_amdgcn_readlane(u.i[0], lane);
  r.i[1] = __builtin_amdgcn_readlane(u.i[1], lane);
  return r.d;
}

// ================= D1: gram + stats, non-atomic per-(chunk,class) partials ==============
__global__ __launch_bounds__(256) void k_front(const float* __restrict__ mu,
                                               const int* __restrict__ labels, char* ws) {
  __shared__ double smem[2176];
  int blk = blockIdx.x;
  int chunk = blk >> 3, c = blk & 7;
  int tid = threadIdx.x;
  int lane = tid & 63, w = tid >> 6;
  int tx = tid & 15, ty = tid >> 4;
  float* rows = (float*)smem;               // [64][64] = 16 KB
  int* labs = (int*)(smem + 2048);
  float* ssum = (float*)(smem + 2080);
  int* scnt = (int*)(smem + 2112);
  int* sfst = (int*)(smem + 2114);
  float* Gpart = (float*)(ws + OFF_GPART);
  float* Spart = (float*)(ws + OFF_SPART);
  int* cpart = (int*)(ws + OFF_CPART);
  int* fpart = (int*)(ws + OFF_FPART);
  if (blk == 0) {                           // zero GT + sync flags for D2 (D1->D2 ordered)
    double* GT = (double*)(ws + OFF_GT);
    for (int i = tid; i < KK * KK; i += 256) GT[i] = 0.0;
    if (tid == 0) {
      *(int*)(ws + OFF_CNTR) = 0;
      *(int*)(ws + OFF_RDY) = 0;
      *(int*)(ws + OFF_FLG) = 0;
    }
  }

  double acc[4][4] = {{0.0}};
  float rsum = 0.f;
  int cnt = 0, first = BB;
  int base = chunk * ROWS_PER_CHUNK;
  const float4* mu4 = (const float4*)mu + (size_t)base * (KK / 4);
  if (tid < KK) ssum[tid] = 0.f;

  float4 pf[4];
  int plab = 0;
#pragma unroll
  for (int i = 0; i < 4; ++i) pf[i] = mu4[tid + i * 256];
  if (tid < 64) plab = labels[base + tid];

#pragma unroll 1
  for (int g = 0; g < ROWS_PER_CHUNK / 64; ++g) {
    __syncthreads();
    float4* rows4 = (float4*)rows;
#pragma unroll
    for (int i = 0; i < 4; ++i) rows4[tid + i * 256] = pf[i];
    if (tid < 64) labs[tid] = plab;
    __syncthreads();
    if (g + 1 < ROWS_PER_CHUNK / 64) {
#pragma unroll
      for (int i = 0; i < 4; ++i) pf[i] = mu4[(g + 1) * 1024 + tid + i * 256];
      if (tid < 64) plab = labels[base + (g + 1) * 64 + tid];
    }
#pragma unroll 4
    for (int r = 0; r < 16; ++r) {
      int rr = w * 16 + r;
      if (labs[rr] == c) rsum += rows[rr * KK + lane];
    }
    if (lane < 16 && labs[w * 16 + lane] == c) {
      cnt++;
      first = min(first, base + g * 64 + w * 16 + lane);
    }
    unsigned long long m = __ballot(labs[lane] == c);
    while (m) {
      int r = __builtin_ctzll(m);
      m &= m - 1;
      const float4* rw4 = (const float4*)(rows + r * KK);
      float4 a4 = rw4[ty], b4 = rw4[tx];
      const float* ai = (const float*)&a4;
      const float* bj = (const float*)&b4;
#pragma unroll
      for (int a = 0; a < 4; ++a)
#pragma unroll
        for (int b = 0; b < 4; ++b) acc[a][b] += (double)ai[a] * (double)bj[b];
    }
  }
  int slot = chunk * CC + c;
  float* Gp = Gpart + (size_t)slot * KK * KK;
#pragma unroll
  for (int a = 0; a < 4; ++a) {
    float4 v = make_float4((float)acc[a][0], (float)acc[a][1], (float)acc[a][2], (float)acc[a][3]);
    *(float4*)(Gp + (ty * 4 + a) * KK + tx * 4) = v;
  }
  atomicAdd(&ssum[lane], rsum);             // LDS-only atomic
#pragma unroll
  for (int off = 32; off; off >>= 1) {
    cnt += __shfl_down(cnt, off);
    first = min(first, __shfl_down(first, off));
  }
  if (lane == 0) { scnt[w] = cnt; sfst[w] = first; }
  __syncthreads();
  if (tid < KK) Spart[(size_t)slot * KK + tid] = ssum[tid];
  if (tid == 0) {
    cpart[slot] = scnt[0] + scnt[1] + scnt[2] + scnt[3];
    fpart[slot] = min(min(sfst[0], sfst[1]), min(sfst[2], sfst[3]));
  }
}

// ================= 4-wave blocked Cholesky (panel=8, rolled); returns logdet ============
__device__ __noinline__ double chol64(double* smem, bool isS2) {
  int tid = threadIdx.x;
  int t = tid & 63, w = tid >> 6;
  double (*bufA)[KK + 1] = (double (*)[KK + 1])(smem + SM_BUFA);
  double (*bufB)[KK + 1] = (double (*)[KK + 1])(smem + SM_BUFB);
  double (*panelb)[KK] = (double (*)[KK])(smem + SM_PANEL);
  double (*Lb)[KK + 1] = (double (*)[KK + 1])(smem + SM_LB);
  double* Ldi = smem + SM_LDI;
  double (*cur)[KK + 1] = bufA;
  double (*nxt)[KK + 1] = bufB;
  double ldacc = 0.0;
  int bound = t | 7;
#pragma unroll 1
  for (int p = 0; p < 8; ++p) {
    const int P0 = p * 8;
    double cc_[8];
#pragma unroll
    for (int m = 0; m < 8; ++m) cc_[m] = cur[t][P0 + m];
    double uu[8];
    double pd = 1.0;
#pragma unroll
    for (int m = 0; m < 8; ++m) {
      double akk = readlane_f64(cc_[m], P0 + m);   // uniform SGPR lane -> v_readlane
      pd *= akk;
      double inv;
      asm("v_rcp_f64 %0, %1" : "=v"(inv) : "v"(akk));
      inv = inv * fma(-akk, inv, 2.0);             // 1 Newton: rel err ~4e-9
      uu[m] = cc_[m] * inv;
      if (w == 0) {
        panelb[m][t] = cc_[m];
        if (isS2) {
          double rsv = sqrt(akk) * inv;            // 1/sqrt(akk)
          Lb[t][P0 + m] = cc_[m] * rsv;
          if (t == 0) Ldi[P0 + m] = rsv;
        }
      }
#pragma unroll
      for (int mm = m + 1; mm < 8; ++mm)
        cc_[mm] -= uu[m] * readlane_f64(cc_[m], P0 + mm);
    }
    ldacc += log(pd);
    __syncthreads();                    // panelb visible
#pragma unroll 1
    for (int jb = p + 1 + w; jb < 8; jb += 4) {
      int j = jb * 8;
      if (j <= bound) {
        double aj[8];
#pragma unroll
        for (int q = 0; q < 8; ++q) aj[q] = cur[t][j + q];
#pragma unroll
        for (int m = 0; m < 8; ++m)
#pragma unroll
          for (int q = 0; q < 8; ++q) aj[q] -= uu[m] * panelb[m][j + q];
#pragma unroll
        for (int q = 0; q < 8; ++q) nxt[t][j + q] = aj[q];
      }
    }
    __syncthreads();
    { auto tmp = cur; cur = nxt; nxt = tmp; }      // 8 swaps -> cur ends == bufA
  }
  return ldacc;                                    // uniform across threads
}

// ================= D2: 9 co-resident blocks; producer/consumer via device atomics ========
__global__ __launch_bounds__(256) void k_back(const float* __restrict__ cov,
                                              float* out, char* ws) {
  __shared__ double smem[SMEM_BACK];
  int blk = blockIdx.x;
  int tid = threadIdx.x;
  int t = tid & 63, w = tid >> 6;
  float* Gpart = (float*)(ws + OFF_GPART);
  float* Spart = (float*)(ws + OFF_SPART);
  int* cpart = (int*)(ws + OFF_CPART);
  int* fpart = (int*)(ws + OFF_FPART);
  double* GT = (double*)(ws + OFF_GT);
  double* invS2 = (double*)(ws + OFF_INV);
  double* ld2g = (double*)(ws + OFF_LD2);
  double* terms = (double*)(ws + OFF_TERMS);
  int* cntr = (int*)(ws + OFF_CNTR);
  int* rdy = (int*)(ws + OFF_RDY);
  int* flg = (int*)(ws + OFF_FLG);
  double* red = smem + SM_BUFB;               // [4][64] scratch (pre-chol only)
  double* mb = smem + SM_MB;
  int* cnt8s = (int*)(smem + SM_INTS);
  int* fst8s = cnt8s + 8;
  const float4* cov4 = (const float4*)cov;

  if (blk < CC) {
    int c = blk;
    // ---- A: stats (own raw sum + total raw sum; all counts/firsts) ----
    if (tid < 64) {
      double so = 0.0, st = 0.0;
#pragma unroll 8
      for (int slot = 0; slot < 128; ++slot) {
        double v = (double)Spart[slot * KK + t];
        st += v;
        if ((slot & 7) == c) so += v;
      }
      smem[SM_MB + t] = so;       // raw; scaled below
      smem[SM_LDI + t] = st;
    } else if (tid < 72) {
      int j = tid - 64;
      int ct = 0, ff = BB;
#pragma unroll
      for (int p = 0; p < NCHUNK; ++p) {
        ct += cpart[p * CC + j];
        ff = min(ff, fpart[p * CC + j]);
      }
      cnt8s[j] = ct;
      fst8s[j] = ff;
    }
    __syncthreads();
    int nc = cnt8s[c];
    double ncd = (double)nc;
    double safe = nc > 0 ? ncd : 1.0;
    double inv_safe = 1.0 / safe;
    if (tid < 64) {
      double m = smem[SM_MB + t] * inv_safe;
      double mt2 = smem[SM_LDI + t] * (1.0 / (double)BB);
      smem[SM_MB + t] = m;
      smem[SM_LDI + t] = mt2 - m;               // dv
    }
    __syncthreads();

    // ---- B: reduce own 16 Gpart slots -> build Sigma_c (bufA + LDS stash) + GT atomics ----
    double* stash = smem + SM_LB;               // [64][65], untouched by chol(!isS2)
#pragma unroll 1
    for (int q = 0; q < 4; ++q) {
      int base_e = tid * 16 + q * 4;
      double s0 = 0.0, s1 = 0.0, s2 = 0.0, s3 = 0.0;
#pragma unroll
      for (int p = 0; p < NCHUNK; ++p) {
        float4 v = ((const float4*)(Gpart + (size_t)(p * CC + c) * KK * KK))[base_e >> 2];
        s0 += (double)v.x; s1 += (double)v.y; s2 += (double)v.z; s3 += (double)v.w;
      }
      int r = base_e >> 6, c0 = base_e & 63;
      float4 cv = cov4[base_e >> 2];
      double mr = mb[r] * ncd;
      double v0 = (double)cv.x + (s0 - mr * mb[c0]) * inv_safe;
      double v1 = (double)cv.y + (s1 - mr * mb[c0 + 1]) * inv_safe;
      double v2 = (double)cv.z + (s2 - mr * mb[c0 + 2]) * inv_safe;
      double v3 = (double)cv.w + (s3 - mr * mb[c0 + 3]) * inv_safe;
      double* ba = smem + SM_BUFA + r * (KK + 1) + c0;
      ba[0] = v0; ba[1] = v1; ba[2] = v2; ba[3] = v3;
      double* sb = stash + r * (KK + 1) + c0;
      sb[0] = v0; sb[1] = v1; sb[2] = v2; sb[3] = v3;
      atomicAdd(&GT[base_e], s0);               // device-scope f64 atomics (32K total)
      atomicAdd(&GT[base_e + 1], s1);
      atomicAdd(&GT[base_e + 2], s2);
      atomicAdd(&GT[base_e + 3], s3);
    }
    __syncthreads();                            // drains this block's GT atomics (vmcnt)
    if (tid == 0) {
      __threadfence();
      atomicAdd(rdy, 1);                        // signal G_c published
    }

    // ---- C: own Cholesky (overlaps block 8's build/chol) ----
    double ld1 = chol64(smem, false);

    // ---- D: wait for invS2, then combine ----
    if (tid == 0) {
      int it = 0;
      while (__hip_atomic_load(flg, __ATOMIC_ACQUIRE, __HIP_MEMORY_SCOPE_AGENT) == 0 &&
             ++it < (1 << 20))
        __builtin_amdgcn_s_sleep(8);
    }
    __syncthreads();
    double ld2 = __hip_atomic_load(ld2g, __ATOMIC_RELAXED, __HIP_MEMORY_SCOPE_AGENT);
    double* dvv = smem + SM_LDI;
    double trp = 0.0, qp = 0.0;
#pragma unroll 4
    for (int rr = 0; rr < 16; ++rr) {
      int r = w * 16 + rr;
      double iv = __hip_atomic_load(&invS2[r * KK + t], __ATOMIC_RELAXED,
                                    __HIP_MEMORY_SCOPE_AGENT);
      trp += iv * stash[r * (KK + 1) + t];
      qp += iv * dvv[r];
    }
    qp *= dvv[t];
#pragma unroll
    for (int m = 32; m; m >>= 1) {
      trp += __shfl_down(trp, m);
      qp += __shfl_down(qp, m);
    }
    double* wred = smem + SM_PANEL;             // dead post-chol
    if (t == 0) { wred[w * 2] = trp; wred[w * 2 + 1] = qp; }
    __syncthreads();
    if (tid == 0) {
      double tr = wred[0] + wred[2] + wred[4] + wred[6];
      double quad = wred[1] + wred[3] + wred[5] + wred[7];
      int best = 0;
      long long bv = -2;
      for (int j = 0; j < CC; ++j) {
        long long v = cnt8s[j] > 0 ? (long long)fst8s[j] : -1;
        if (v > bv) { bv = v; best = j; }       // strict > == argmax tie-break
      }
      double kl = 0.5 * (tr + quad - (double)KK + ld2 - ld1);
      double wgt = (nc > 0 && c != best) ? ncd : 0.0;
      double term = kl * wgt / (double)BB;
      atomicExch((unsigned long long*)&terms[c],
                 (unsigned long long)__double_as_longlong(term));
      __threadfence();
      int old = atomicAdd(cntr, 1);
      if (old == CC - 1) {                      // last arriver gathers + writes
        double s = 0.0;
        for (int j = 0; j < CC; ++j) s += atomicAdd(&terms[j], 0.0);
        out[0] = (float)s;
      }
    }
  } else {
    // ---- block 8: total mean ----
    {
      double s = 0.0;
#pragma unroll 8
      for (int p = 0; p < 32; ++p) s += (double)Spart[(w * 32 + p) * KK + t];
      red[w * KK + t] = s;
    }
    __syncthreads();
    if (tid < 64)
      mb[t] = (red[t] + red[KK + t] + red[2 * KK + t] + red[3 * KK + t]) / (double)BB;
    // ---- wait for all 8 G_c contributions ----
    if (tid == 0) {
      int it = 0;
      while (__hip_atomic_load(rdy, __ATOMIC_ACQUIRE, __HIP_MEMORY_SCOPE_AGENT) < CC &&
             ++it < (1 << 20))
        __builtin_amdgcn_s_sleep(8);
    }
    __syncthreads();
    // ---- build Sigma_total from GT (32 KB) ----
    const double invB = 1.0 / (double)BB;
#pragma unroll 1
    for (int q = 0; q < 4; ++q) {
      int base_e = tid * 16 + q * 4;
      int r = base_e >> 6, c0 = base_e & 63;
      float4 cv = cov4[base_e >> 2];
      double mr = mb[r];
      double g0 = __hip_atomic_load(&GT[base_e], __ATOMIC_RELAXED, __HIP_MEMORY_SCOPE_AGENT);
      double g1 = __hip_atomic_load(&GT[base_e + 1], __ATOMIC_RELAXED, __HIP_MEMORY_SCOPE_AGENT);
      double g2 = __hip_atomic_load(&GT[base_e + 2], __ATOMIC_RELAXED, __HIP_MEMORY_SCOPE_AGENT);
      double g3 = __hip_atomic_load(&GT[base_e + 3], __ATOMIC_RELAXED, __HIP_MEMORY_SCOPE_AGENT);
      double* ba = smem + SM_BUFA + r * (KK + 1) + c0;
      ba[0] = (double)cv.x + g0 * invB - mr * mb[c0];
      ba[1] = (double)cv.y + g1 * invB - mr * mb[c0 + 1];
      ba[2] = (double)cv.z + g2 * invB - mr * mb[c0 + 2];
      ba[3] = (double)cv.w + g3 * invB - mr * mb[c0 + 3];
    }
    __syncthreads();
    double ld2 = chol64(smem, true);
    // ---- X = L^{-1} (wave 0; Xs stride-64 overlays dead bufA) ----
    double (*Xs)[KK] = (double (*)[KK])(smem + SM_BUFA);
    if (w == 0) {
      double (*Lb)[KK + 1] = (double (*)[KK + 1])(smem + SM_LB);
      double* Ldi = smem + SM_LDI;
#pragma unroll 1
      for (int g = 0; g < 8; ++g) {
        int I0 = g * 8;
        double sv[8];
#pragma unroll
        for (int m = 0; m < 8; ++m) sv[m] = 0.0;
#pragma unroll 2
        for (int j = 0; j < I0; ++j) {
          double xj = Xs[j][t];                 // lane-consecutive
#pragma unroll
          for (int m = 0; m < 8; ++m) sv[m] += Lb[I0 + m][j] * xj;  // broadcast
        }
#pragma unroll
        for (int m = 0; m < 8; ++m) {
          int i = I0 + m;
          double x = (((i == t) ? 1.0 : 0.0) - sv[m]) * Ldi[i];
#pragma unroll
          for (int mm = m + 1; mm < 8; ++mm) sv[mm] += Lb[I0 + mm][i] * x;
          Xs[i][t] = x;                         // zeros for i<t fall out naturally
        }
      }
    }
    __syncthreads();
    // ---- invS2 = X^T X (agent-scope stores) ----
#pragma unroll 1
    for (int rr = 0; rr < 16; ++rr) {
      int r = w + rr * 4;
      int k0 = r > t ? r : t;
      double s = 0.0;
#pragma unroll 2
      for (int k = k0; k < KK; ++k) s += Xs[k][r] * Xs[k][t];
      __hip_atomic_store(&invS2[r * KK + t], s, __ATOMIC_RELAXED, __HIP_MEMORY_SCOPE_AGENT);
    }
    __syncthreads();                            // drains stores (vmcnt)
    if (tid == 0) {
      __hip_atomic_store(ld2g, ld2, __ATOMIC_RELAXED, __HIP_MEMORY_SCOPE_AGENT);
      __threadfence();
      __hip_atomic_store(flg, 1, __ATOMIC_RELEASE, __HIP_MEMORY_SCOPE_AGENT);
    }
  }
}

extern "C" void kernel_launch(void* const* d_in, const int* in_sizes, int n_in,
                              void* d_out, int out_size, void* d_ws, size_t ws_size,
                              hipStream_t stream) {
  (void)in_sizes; (void)n_in; (void)out_size; (void)ws_size;
  const float* mu = (const float*)d_in[0];
  const int* labels = (const int*)d_in[1];
  const float* cov = (const float*)d_in[2];
  float* out = (float*)d_out;
  char* ws = (char*)d_ws;

  k_front<<<NGBLK, 256, 0, stream>>>(mu, labels, ws);
  k_back<<<CC + 1, 256, 0, stream>>>(cov, out, ws);
}